// Round 3
// baseline (7436.451 us; speedup 1.0000x reference)
//
#include <hip/hip_runtime.h>
#include <cstdint>
#include <cstddef>

static constexpr int T_STEPS = 2048;
static constexpr int BATCH   = 32;
static constexpr int DIM     = 256;   // input dim == hidden dim
static constexpr int NCOL    = 512;   // pre columns actually used (h-gate, t-gate)
static constexpr size_t M_ROWS = (size_t)T_STEPS * BATCH;  // 65536

typedef _Float16 h2_t  __attribute__((ext_vector_type(2)));
typedef _Float16 f16x8 __attribute__((ext_vector_type(8)));
typedef float    f32x4 __attribute__((ext_vector_type(4)));

struct alignas(16) H8 { h2_t a, b, c, d; };
struct alignas(8)  H4 { _Float16 x, y, z, w; };

// ---- workspace layout (bytes) ----
static constexpr size_t XW_OFF = 0;                            // XW f16 [65536][512]
static constexpr size_t A_OFF  = M_ROWS * NCOL * 2;            // A/out0 f16 [65536][256]
static constexpr size_t B0_OFF = A_OFF + M_ROWS * DIM * 2;     // blob0
static constexpr size_t B1_OFF = B0_OFF + (size_t)DIM * NCOL * 2;

__device__ __forceinline__ float fdot2(h2_t a, h2_t b, float c) {
  return __builtin_amdgcn_fdot2(a, b, c, false);
}

// ---------------- prep: f32 -> f16 convert (input) ----------------
__global__ void cvt_f32_to_f16(const float* __restrict__ src, _Float16* __restrict__ dst, int n4) {
  int i = blockIdx.x * blockDim.x + threadIdx.x;
  if (i >= n4) return;
  float4 v = ((const float4*)src)[i];
  H4 o; o.x = (_Float16)v.x; o.y = (_Float16)v.y; o.z = (_Float16)v.z; o.w = (_Float16)v.w;
  ((H4*)dst)[i] = o;
}

// ---------------- prep: Wih -> MFMA B-fragment blob ----------------
// blob[nt][kc][lane][j] = B[kc*32 + (lane>>4)*8 + j][nt*16 + (lane&15)],  B = Wih[:, 0:512]
__global__ void prep_blobs(const float* __restrict__ wih0, const float* __restrict__ wih1,
                           _Float16* __restrict__ blob0, _Float16* __restrict__ blob1) {
  int gid = blockIdx.x * blockDim.x + threadIdx.x;   // < 2*256*512
  int mat = gid >> 17;
  int rem = gid & 131071;
  int k = rem >> 9;        // 0..255
  int n = rem & 511;       // 0..511
  float v = (mat ? wih1 : wih0)[k * 768 + n];
  int kc = k >> 5, q = (k >> 3) & 3, j = k & 7, nt = n >> 4;
  int lane = (n & 15) + 16 * q;
  _Float16* b = mat ? blob1 : blob0;
  b[((size_t)(nt * 8 + kc) * 64 + lane) * 8 + j] = (_Float16)v;
}

// ---------------- GEMM: XW = A[65536,256] @ B[256,512]  (f16 MFMA, f32 acc) ----------------
__global__ __launch_bounds__(256) void gemm_xw(const _Float16* __restrict__ A,
                                               const _Float16* __restrict__ blob,
                                               _Float16* __restrict__ XW) {
  int lane = threadIdx.x & 63;
  int wave = threadIdx.x >> 6;
  int wid  = blockIdx.x * 4 + wave;       // 0..8191
  int mbase = (wid >> 1) * 16;
  int nhalf = wid & 1;
  int q = lane >> 4, n15 = lane & 15;

  f32x4 acc[16];
#pragma unroll
  for (int i = 0; i < 16; i++) acc[i] = (f32x4){0.f, 0.f, 0.f, 0.f};

  const _Float16* Arow = A + (size_t)(mbase + n15) * DIM + q * 8;
#pragma unroll
  for (int kc = 0; kc < 8; kc++) {
    f16x8 af = *(const f16x8*)(Arow + kc * 32);
#pragma unroll
    for (int nt = 0; nt < 16; nt++) {
      const _Float16* bp = blob + ((size_t)((nhalf * 16 + nt) * 8 + kc) * 64 + lane) * 8;
      f16x8 bf = *(const f16x8*)bp;
      acc[nt] = __builtin_amdgcn_mfma_f32_16x16x32_f16(af, bf, acc[nt], 0, 0, 0);
    }
  }
#pragma unroll
  for (int nt = 0; nt < 16; nt++) {
#pragma unroll
    for (int r = 0; r < 4; r++) {
      int m   = mbase + q * 4 + r;
      int col = nhalf * 256 + nt * 16 + n15;
      XW[(size_t)m * NCOL + col] = (_Float16)acc[nt][r];
    }
  }
}

// ---------------- recurrence ----------------
__device__ __forceinline__ int read_len(const void* p, int b) {
  const long long* q = (const long long*)p;
  bool ok64 = true;
  for (int i = 0; i < 32; i++) { long long v = q[i]; if (v < 0 || v > 2048) ok64 = false; }
  return ok64 ? (int)q[b] : ((const int*)p)[b];
}

__device__ __forceinline__ float sigmoidf_(float x) { return 1.f / (1.f + __expf(-x)); }
__device__ __forceinline__ float tanhf_(float x) {
  float e = __expf(-2.f * fabsf(x));
  float t = (1.f - e) / (1.f + e);
  return copysignf(t, x);
}

// 256 threads (4 waves). Thread j owns BOTH pre columns j (h-gate) and j+256
// (t-gate): one LDS broadcast read of h feeds 8 dot2s (4 per column), halving
// LDS-pipe instruction count vs 8-wave/1-col layout, and removing all
// cross-lane exchange. Whh cols j and j+256 live in 256 packed-f16 VGPRs.
template <int LAYER>
__global__ __launch_bounds__(256, 1) void recur(const _Float16* __restrict__ xw,
                                                const float* __restrict__ whh,
                                                const float* __restrict__ bias,
                                                const void* __restrict__ lenp,
                                                _Float16* __restrict__ out0,
                                                float* __restrict__ out1,
                                                float* __restrict__ hn) {
  int b = blockIdx.x;
  int j = threadIdx.x;          // h-col; t-col = j + 256
  int len = read_len(lenp, b);

  h2_t wh[128], wt[128];
#pragma unroll
  for (int kk = 0; kk < 128; kk++) {
    float h0 = whh[(size_t)(2 * kk) * 768 + j];
    float h1 = whh[(size_t)(2 * kk + 1) * 768 + j];
    float t0 = whh[(size_t)(2 * kk) * 768 + j + 256];
    float t1 = whh[(size_t)(2 * kk + 1) * 768 + j + 256];
    h2_t ph; ph[0] = (_Float16)h0; ph[1] = (_Float16)h1; wh[kk] = ph;
    h2_t pt; pt[0] = (_Float16)t0; pt[1] = (_Float16)t1; wt[kk] = pt;
  }
  float bjh = bias[j];
  float bjt = bias[j + 256];

  __shared__ __align__(16) _Float16 hs[2][DIM];  // ping-pong h buffers (f16)
  hs[0][j] = (_Float16)0.f;
  float hown = 0.f;
  __syncthreads();

  const _Float16* xcolh = xw + (size_t)b * NCOL + j;
  const _Float16* xcolt = xcolh + 256;
  float xvh_n = (len > 0) ? (float)xcolh[0] : 0.f;
  float xvt_n = (len > 0) ? (float)xcolt[0] : 0.f;
  int p = 0;

  for (int t = 0; t < len; t++) {
    float xvh = xvh_n, xvt = xvt_n;
    size_t toff = (size_t)((t + 1 < len) ? (t + 1) : t) * (BATCH * NCOL);
    xvh_n = (float)xcolh[toff];              // prefetch next step
    xvt_n = (float)xcolt[toff];

    float a0 = 0.f, a1 = 0.f, a2 = 0.f, a3 = 0.f;
    float c0 = 0.f, c1 = 0.f, c2 = 0.f, c3 = 0.f;
    const H8* hp = (const H8*)hs[p];
#pragma unroll
    for (int m = 0; m < 32; m++) {
      H8 hh = hp[m];                         // one broadcast b128 -> 8 dot2
      a0 = fdot2(hh.a, wh[4 * m + 0], a0);
      c0 = fdot2(hh.a, wt[4 * m + 0], c0);
      a1 = fdot2(hh.b, wh[4 * m + 1], a1);
      c1 = fdot2(hh.b, wt[4 * m + 1], c1);
      a2 = fdot2(hh.c, wh[4 * m + 2], a2);
      c2 = fdot2(hh.c, wt[4 * m + 2], c2);
      a3 = fdot2(hh.d, wh[4 * m + 3], a3);
      c3 = fdot2(hh.d, wt[4 * m + 3], c3);
    }
    float pre_h = (a0 + a1) + (a2 + a3) + xvh + bjh;
    float pre_t = (c0 + c1) + (c2 + c3) + xvt + bjt;

    float tg = sigmoidf_(pre_t);
    float cg = sigmoidf_(tg);                // bug-faithful: sigmoid of sigmoid
    float s  = tanhf_(pre_h) * tg + hown * cg;
    hown = s;
    hs[1 - p][j] = (_Float16)s;
    if (LAYER == 0)
      out0[((size_t)t * BATCH + b) * DIM + j] = (_Float16)s;
    else
      out1[((size_t)t * BATCH + b) * DIM + j] = s;
    __syncthreads();
    p ^= 1;
  }

  hn[LAYER * (BATCH * DIM) + b * DIM + j] = hown;
  if (LAYER == 1) {
    for (int t = len; t < T_STEPS; t++)      // frozen region: out = frozen h
      out1[((size_t)t * BATCH + b) * DIM + j] = hown;
  }
}

extern "C" void kernel_launch(void* const* d_in, const int* in_sizes, int n_in,
                              void* d_out, int out_size, void* d_ws, size_t ws_size,
                              hipStream_t stream) {
  const float* input_ = (const float*)d_in[0];
  const void*  lenp   = d_in[1];
  const float* Wih0   = (const float*)d_in[2];
  const float* Whh0   = (const float*)d_in[3];
  const float* b0     = (const float*)d_in[4];
  const float* Wih1   = (const float*)d_in[5];
  const float* Whh1   = (const float*)d_in[6];
  const float* b1     = (const float*)d_in[7];
  float* out = (float*)d_out;
  char*  ws  = (char*)d_ws;

  _Float16* XW    = (_Float16*)(ws + XW_OFF);
  _Float16* Abuf  = (_Float16*)(ws + A_OFF);
  _Float16* blob0 = (_Float16*)(ws + B0_OFF);
  _Float16* blob1 = (_Float16*)(ws + B1_OFF);
  float* hn = out + M_ROWS * DIM;   // d_out tail: h_n [2][32][256]

  cvt_f32_to_f16<<<16384, 256, 0, stream>>>(input_, Abuf, (int)(M_ROWS * DIM / 4));
  prep_blobs<<<1024, 256, 0, stream>>>(Wih0, Wih1, blob0, blob1);
  gemm_xw<<<2048, 256, 0, stream>>>(Abuf, blob0, XW);
  recur<0><<<32, 256, 0, stream>>>(XW, Whh0, b0, lenp, Abuf, nullptr, hn);
  gemm_xw<<<2048, 256, 0, stream>>>(Abuf, blob1, XW);
  recur<1><<<32, 256, 0, stream>>>(XW, Whh1, b1, lenp, nullptr, out, hn);
}

// Round 4
// 5221.044 us; speedup vs baseline: 1.4243x; 1.4243x over previous
//
#include <hip/hip_runtime.h>
#include <cstdint>
#include <cstddef>

static constexpr int T_STEPS = 2048;
static constexpr int BATCH   = 32;
static constexpr int DIM     = 256;
static constexpr int NCOL    = 512;
static constexpr size_t M_ROWS = (size_t)T_STEPS * BATCH;   // 65536

typedef _Float16 f16x4 __attribute__((ext_vector_type(4)));
typedef _Float16 f16x8 __attribute__((ext_vector_type(8)));
typedef float    f32x4 __attribute__((ext_vector_type(4)));
struct alignas(8) H4 { _Float16 x, y, z, w; };

// ---- workspace layout (bytes) ----
static constexpr size_t XW_OFF   = 0;                           // XW2 f16 [2048][2][32][64][4] = 64 MB
static constexpr size_t A_OFF    = M_ROWS * NCOL * 2;           // Abuf f16 [65536][256] = 32 MB
static constexpr size_t BLOB_OFF = A_OFF + M_ROWS * DIM * 2;    // 4 blobs x 256 KB
static constexpr size_t BLOB_ELT = (size_t)DIM * NCOL;          // 131072 f16 per blob

// ---------------- prep: f32 -> f16 convert (input) ----------------
__global__ void cvt_f32_to_f16(const float* __restrict__ src, _Float16* __restrict__ dst, int n4) {
  int i = blockIdx.x * blockDim.x + threadIdx.x;
  if (i >= n4) return;
  float4 v = ((const float4*)src)[i];
  H4 o; o.x = (_Float16)v.x; o.y = (_Float16)v.y; o.z = (_Float16)v.z; o.w = (_Float16)v.w;
  ((H4*)dst)[i] = o;
}

// ---------------- prep: W -> MFMA B-fragment blobs (cols 0:512 of [256][768]) ----
// blob[tn][kc][lane][j] = W[kc*32 + (lane>>4)*8 + j][tn*16 + (lane&15)]
__global__ void prep_blobs4(const float* __restrict__ w0, const float* __restrict__ w1,
                            const float* __restrict__ w2, const float* __restrict__ w3,
                            _Float16* __restrict__ blobs) {
  int gid = blockIdx.x * blockDim.x + threadIdx.x;   // < 4*131072
  int mat = gid >> 17;
  int rem = gid & 131071;
  int k = rem >> 9;        // 0..255
  int n = rem & 511;       // 0..511
  const float* src = (mat == 0) ? w0 : (mat == 1) ? w1 : (mat == 2) ? w2 : w3;
  float v = src[k * 768 + n];
  int kc = k >> 5, q = (k >> 3) & 3, j = k & 7, tn = n >> 4;
  int lane = (n & 15) + 16 * q;
  blobs[(size_t)mat * BLOB_ELT + ((size_t)(tn * 8 + kc) * 64 + lane) * 8 + j] = (_Float16)v;
}

// ---------------- GEMM: XW2 = A[65536,256] @ B[256,512] + bias, stored in recur layout ----
// XW2 f16 [t][wg][tn(32)][lane(64)][reg(4)]  (the exact MFMA C/D fragment order)
__global__ __launch_bounds__(256) void gemm_xw(const _Float16* __restrict__ A,
                                               const _Float16* __restrict__ blob,
                                               const float* __restrict__ bias,
                                               _Float16* __restrict__ XW2) {
  int lane = threadIdx.x & 63;
  int wave = threadIdx.x >> 6;
  int wid  = blockIdx.x * 4 + wave;       // 0..8191
  int mbase = (wid >> 1) * 16;
  int nhalf = wid & 1;
  int q = lane >> 4, n15 = lane & 15;
  int t  = mbase >> 5;
  int wg = (mbase >> 4) & 1;

  f32x4 acc[16];
#pragma unroll
  for (int i = 0; i < 16; i++) acc[i] = (f32x4){0.f, 0.f, 0.f, 0.f};

  const _Float16* Arow = A + (size_t)(mbase + n15) * DIM + q * 8;
#pragma unroll
  for (int kc = 0; kc < 8; kc++) {
    f16x8 af = *(const f16x8*)(Arow + kc * 32);
#pragma unroll
    for (int nt = 0; nt < 16; nt++) {
      const _Float16* bp = blob + ((size_t)((nhalf * 16 + nt) * 8 + kc) * 64 + lane) * 8;
      f16x8 bf = *(const f16x8*)bp;
      acc[nt] = __builtin_amdgcn_mfma_f32_16x16x32_f16(af, bf, acc[nt], 0, 0, 0);
    }
  }
#pragma unroll
  for (int nt = 0; nt < 16; nt++) {
    float bv = bias[nhalf * 256 + nt * 16 + n15];
    int tn = nhalf * 16 + nt;
    f16x4 o;
#pragma unroll
    for (int r = 0; r < 4; r++) o[r] = (_Float16)(acc[nt][r] + bv);
    *(f16x4*)(XW2 + ((size_t)((t * 2 + wg) * 32 + tn) * 64 + lane) * 4) = o;
  }
}

// ---------------- recurrence (MFMA) ----------------
__device__ __forceinline__ int read_len(const void* p, int b) {
  const long long* q = (const long long*)p;
  bool ok64 = true;
  for (int i = 0; i < 32; i++) { long long v = q[i]; if (v < 0 || v > 2048) ok64 = false; }
  return ok64 ? (int)q[b] : ((const int*)p)[b];
}

// 2 WGs x 16 batches; 8 waves. Wave w owns N-tiles {2w,2w+1} (h-gate cols
// 32w..32w+31) and {16+2w,17+2w} (t-gate, +256). Whh frags resident in VGPRs;
// h ping-pongs through an A-fragment LDS buffer; ONE barrier per step.
// Gate pair (pre_h, pre_t) for an element lives in the same lane/reg -> no
// exchange; h_prev lives in registers (C/D ownership is step-invariant).
template <int LAYER>
__global__ __launch_bounds__(512, 2) void recur(const _Float16* __restrict__ xw2,
                                                const _Float16* __restrict__ bblob,
                                                const void* __restrict__ lenp,
                                                _Float16* __restrict__ out0,
                                                float* __restrict__ out1,
                                                float* __restrict__ hn) {
  const int wg  = blockIdx.x;              // 0..1
  const int tid = threadIdx.x;
  const int w   = tid >> 6;                // wave 0..7
  const int lane = tid & 63;
  const int q = lane >> 4, l15 = lane & 15;

  int lenv[4];
#pragma unroll
  for (int r = 0; r < 4; r++) lenv[r] = read_len(lenp, wg * 16 + q * 4 + r);

  // Whh B-fragments: [pair pp][kc] for h tiles (2w+pp) and t tiles (16+2w+pp)
  f16x8 Bh[2][8], Bt[2][8];
#pragma unroll
  for (int pp = 0; pp < 2; pp++)
#pragma unroll
    for (int kc = 0; kc < 8; kc++) {
      Bh[pp][kc] = *(const f16x8*)(bblob + ((size_t)((2 * w + pp) * 8 + kc) * 64 + lane) * 8);
      Bt[pp][kc] = *(const f16x8*)(bblob + ((size_t)((16 + 2 * w + pp) * 8 + kc) * 64 + lane) * 8);
    }

  __shared__ __align__(16) _Float16 hfrag[2][8][64][8];   // ping-pong A-frag buffers
  ((f16x8*)&hfrag[0][0][0][0])[tid] = (f16x8)(_Float16)0.f;  // zero hfrag[0]
  __syncthreads();

  // per-element constants (pp in 0..1, r in 0..3): LDS write slot, out column
  int lslot[2], cofs[2];
#pragma unroll
  for (int pp = 0; pp < 2; pp++) {
    int c = (2 * w + pp) * 16 + l15;                   // h-col in [32w, 32w+32)
    cofs[pp] = c;
    lslot[pp] = 16 * ((((2 * w + pp) * 2) + (l15 >> 3)) & 3);  // + (q*4+r) added per r
  }

  float hprev[8] = {0.f, 0.f, 0.f, 0.f, 0.f, 0.f, 0.f, 0.f};   // [pp*4+r]
  const float K1 = 1.442695040888963f, K2 = 2.885390081777927f;

  const _Float16* xbase = xw2 + (size_t)wg * 32 * 64 * 4 + (size_t)lane * 4;
  auto xaddr = [&](int t, int tn) -> const f16x4* {
    return (const f16x4*)(xbase + ((size_t)t * 64 + tn) * 64 * 4);
  };
  f16x4 xw_n[4];
  xw_n[0] = *xaddr(0, 2 * w);     xw_n[1] = *xaddr(0, 2 * w + 1);
  xw_n[2] = *xaddr(0, 16 + 2 * w); xw_n[3] = *xaddr(0, 17 + 2 * w);

  for (int t = 0; t < T_STEPS; t++) {
    f16x4 xw_c[4];
#pragma unroll
    for (int i = 0; i < 4; i++) xw_c[i] = xw_n[i];
    int tn_ = (t + 1 < T_STEPS) ? t + 1 : t;          // prefetch next step
    xw_n[0] = *xaddr(tn_, 2 * w);      xw_n[1] = *xaddr(tn_, 2 * w + 1);
    xw_n[2] = *xaddr(tn_, 16 + 2 * w); xw_n[3] = *xaddr(tn_, 17 + 2 * w);

    const int p = t & 1;
    // C-init from xw (bias already folded in by gemm)
    f32x4 acc[4];
#pragma unroll
    for (int i = 0; i < 4; i++) {
      f32x4 c; 
#pragma unroll
      for (int r = 0; r < 4; r++) c[r] = (float)xw_c[i][r];
      acc[i] = c;
    }
    const f16x8* Ap = (const f16x8*)&hfrag[p][0][0][0];
#pragma unroll
    for (int kc = 0; kc < 8; kc++) {
      f16x8 a = Ap[kc * 64 + lane];
      acc[0] = __builtin_amdgcn_mfma_f32_16x16x32_f16(a, Bh[0][kc], acc[0], 0, 0, 0);
      acc[1] = __builtin_amdgcn_mfma_f32_16x16x32_f16(a, Bh[1][kc], acc[1], 0, 0, 0);
      acc[2] = __builtin_amdgcn_mfma_f32_16x16x32_f16(a, Bt[0][kc], acc[2], 0, 0, 0);
      acc[3] = __builtin_amdgcn_mfma_f32_16x16x32_f16(a, Bt[1][kc], acc[3], 0, 0, 0);
    }

    _Float16* hw = &hfrag[1 - p][w][0][0];            // this wave writes kc == w block
#pragma unroll
    for (int pp = 0; pp < 2; pp++) {
#pragma unroll
      for (int r = 0; r < 4; r++) {
        float ph = acc[pp][r];
        float pt = acc[2 + pp][r];
        float phc = fminf(fmaxf(ph, -20.f), 20.f);
        float e1 = __builtin_amdgcn_exp2f(-K2 * phc);
        float e2 = __builtin_amdgcn_exp2f(-K1 * pt);
        float u1 = 1.f + e1;
        float d  = u1 * (1.f + e2);
        float rr = __builtin_amdgcn_rcpf(d);
        float ttg = (1.f - e1) * rr;                  // tanh(ph)*tg
        float tg  = u1 * rr;                          // sigmoid(pt)
        // cg = sigmoid(tg), tg in [0,1]: cubic fit, |err| < 2e-4
        float cg = 0.5f + tg * (0.250905f + tg * (-0.00432f + tg * (-0.015525f)));
        float idx_h = hprev[pp * 4 + r];
        float s = ttg + idx_h * cg;
        bool live = t < lenv[r];
        s = live ? s : idx_h;
        hprev[pp * 4 + r] = s;
        _Float16 s16 = (_Float16)s;
        hw[(lslot[pp] + q * 4 + r) * 8 + (l15 & 7)] = s16;
        size_t oidx = ((size_t)t * BATCH + wg * 16 + q * 4 + r) * DIM + cofs[pp];
        if (LAYER == 0) out0[oidx] = s16;
        else            out1[oidx] = s;
      }
    }
    __syncthreads();
  }

#pragma unroll
  for (int pp = 0; pp < 2; pp++)
#pragma unroll
    for (int r = 0; r < 4; r++)
      hn[LAYER * (BATCH * DIM) + (wg * 16 + q * 4 + r) * DIM + cofs[pp]] = hprev[pp * 4 + r];
}

extern "C" void kernel_launch(void* const* d_in, const int* in_sizes, int n_in,
                              void* d_out, int out_size, void* d_ws, size_t ws_size,
                              hipStream_t stream) {
  const float* input_ = (const float*)d_in[0];
  const void*  lenp   = d_in[1];
  const float* Wih0   = (const float*)d_in[2];
  const float* Whh0   = (const float*)d_in[3];
  const float* b0     = (const float*)d_in[4];
  const float* Wih1   = (const float*)d_in[5];
  const float* Whh1   = (const float*)d_in[6];
  const float* b1     = (const float*)d_in[7];
  float* out = (float*)d_out;
  char*  ws  = (char*)d_ws;

  _Float16* XW2   = (_Float16*)(ws + XW_OFF);
  _Float16* Abuf  = (_Float16*)(ws + A_OFF);
  _Float16* blobs = (_Float16*)(ws + BLOB_OFF);   // [Wih0, Wih1, Whh0, Whh1]
  float* hn = out + M_ROWS * DIM;                 // d_out tail: h_n [2][32][256]

  cvt_f32_to_f16<<<16384, 256, 0, stream>>>(input_, Abuf, (int)(M_ROWS * DIM / 4));
  prep_blobs4<<<2048, 256, 0, stream>>>(Wih0, Wih1, Whh0, Whh1, blobs);
  gemm_xw<<<2048, 256, 0, stream>>>(Abuf, blobs + 0 * BLOB_ELT, b0, XW2);
  recur<0><<<2, 512, 0, stream>>>(XW2, blobs + 2 * BLOB_ELT, lenp, Abuf, nullptr, hn);
  gemm_xw<<<2048, 256, 0, stream>>>(Abuf, blobs + 1 * BLOB_ELT, b1, XW2);
  recur<1><<<2, 512, 0, stream>>>(XW2, blobs + 3 * BLOB_ELT, lenp, nullptr, out, hn);
}

// Round 5
// 3633.904 us; speedup vs baseline: 2.0464x; 1.4368x over previous
//
#include <hip/hip_runtime.h>
#include <cstdint>
#include <cstddef>

static constexpr int T_STEPS = 2048;
static constexpr int BATCH   = 32;
static constexpr int DIM     = 256;
static constexpr int NCOL    = 512;
static constexpr size_t M_ROWS = (size_t)T_STEPS * BATCH;   // 65536

typedef _Float16 f16x4 __attribute__((ext_vector_type(4)));
typedef _Float16 f16x8 __attribute__((ext_vector_type(8)));
typedef float    f32x4 __attribute__((ext_vector_type(4)));
struct alignas(8) H4 { _Float16 x, y, z, w; };

// ---- workspace layout (bytes) ----
static constexpr size_t XW_OFF   = 0;                           // XW f16 [65536][512] (bias folded) = 64 MB
static constexpr size_t A_OFF    = M_ROWS * NCOL * 2;           // Abuf f16 [65536][256] = 32 MB
static constexpr size_t BLOB_OFF = A_OFF + M_ROWS * DIM * 2;    // 4 blobs x 256 KB
static constexpr size_t BLOB_ELT = (size_t)DIM * NCOL;          // 131072 f16 per blob

// ---------------- prep: f32 -> f16 convert (input) ----------------
__global__ void cvt_f32_to_f16(const float* __restrict__ src, _Float16* __restrict__ dst, int n4) {
  int i = blockIdx.x * blockDim.x + threadIdx.x;
  if (i >= n4) return;
  float4 v = ((const float4*)src)[i];
  H4 o; o.x = (_Float16)v.x; o.y = (_Float16)v.y; o.z = (_Float16)v.z; o.w = (_Float16)v.w;
  ((H4*)dst)[i] = o;
}

// ---------------- prep: W -> MFMA B-fragment blobs (cols 0:512 of [256][768]) ----
// blob[tn][kc][lane][j] = W[kc*32 + (lane>>4)*8 + j][tn*16 + (lane&15)]
__global__ void prep_blobs4(const float* __restrict__ w0, const float* __restrict__ w1,
                            const float* __restrict__ w2, const float* __restrict__ w3,
                            _Float16* __restrict__ blobs) {
  int gid = blockIdx.x * blockDim.x + threadIdx.x;   // < 4*131072
  int mat = gid >> 17;
  int rem = gid & 131071;
  int k = rem >> 9;        // 0..255
  int n = rem & 511;       // 0..511
  const float* src = (mat == 0) ? w0 : (mat == 1) ? w1 : (mat == 2) ? w2 : w3;
  float v = src[k * 768 + n];
  int kc = k >> 5, q = (k >> 3) & 3, j = k & 7, tn = n >> 4;
  int lane = (n & 15) + 16 * q;
  blobs[(size_t)mat * BLOB_ELT + ((size_t)(tn * 8 + kc) * 64 + lane) * 8 + j] = (_Float16)v;
}

// ---------------- GEMM: XW = A[65536,256] @ B[256,512] + bias, row-major f16 ----
__global__ __launch_bounds__(256) void gemm_xw(const _Float16* __restrict__ A,
                                               const _Float16* __restrict__ blob,
                                               const float* __restrict__ bias,
                                               _Float16* __restrict__ XW) {
  int lane = threadIdx.x & 63;
  int wave = threadIdx.x >> 6;
  int wid  = blockIdx.x * 4 + wave;       // 0..8191
  int mbase = (wid >> 1) * 16;
  int nhalf = wid & 1;
  int q = lane >> 4, n15 = lane & 15;

  f32x4 acc[16];
#pragma unroll
  for (int i = 0; i < 16; i++) acc[i] = (f32x4){0.f, 0.f, 0.f, 0.f};

  const _Float16* Arow = A + (size_t)(mbase + n15) * DIM + q * 8;
#pragma unroll
  for (int kc = 0; kc < 8; kc++) {
    f16x8 af = *(const f16x8*)(Arow + kc * 32);
#pragma unroll
    for (int nt = 0; nt < 16; nt++) {
      const _Float16* bp = blob + ((size_t)((nhalf * 16 + nt) * 8 + kc) * 64 + lane) * 8;
      f16x8 bf = *(const f16x8*)bp;
      acc[nt] = __builtin_amdgcn_mfma_f32_16x16x32_f16(af, bf, acc[nt], 0, 0, 0);
    }
  }
#pragma unroll
  for (int nt = 0; nt < 16; nt++) {
    int col = nhalf * 256 + nt * 16 + n15;
    float bv = bias[col];
#pragma unroll
    for (int r = 0; r < 4; r++) {
      int m = mbase + q * 4 + r;
      XW[(size_t)m * NCOL + col] = (_Float16)(acc[nt][r] + bv);
    }
  }
}

// ---------------- recurrence (batch-per-WG MFMA GEMV) ----------------
__device__ __forceinline__ int read_len(const void* p, int b) {
  const long long* q = (const long long*)p;
  bool ok64 = true;
  for (int i = 0; i < 32; i++) { long long v = q[i]; if (v < 0 || v > 2048) ok64 = false; }
  return ok64 ? (int)q[b] : ((const int*)p)[b];
}

// 32 WGs (one batch each), 512 threads = 8 waves, 2 waves/SIMD.
// Wave w owns N-tiles {2w, 2w+1} (h-gate cols 32w..32w+31) and {16+2w, 17+2w}
// (matching t-gate cols +256). M=1 GEMV via 16x16x32 MFMA: every lane's
// A-frag is h[kc*32 + q*8 .. +7], so ALL 16 output rows are duplicates ->
// every lane/reg holds a valid pre[col]; no exchange, no masking in compute.
// h round-trips through a 256-elem f16 LDS buffer (ping-pong, ONE barrier).
template <int LAYER>
__global__ __launch_bounds__(512, 2) void recur(const _Float16* __restrict__ xw,
                                                const _Float16* __restrict__ bblob,
                                                const void* __restrict__ lenp,
                                                _Float16* __restrict__ out0,
                                                float* __restrict__ out1,
                                                float* __restrict__ hn) {
  const int b    = blockIdx.x;             // batch
  const int tid  = threadIdx.x;
  const int w    = tid >> 6;               // wave 0..7
  const int lane = tid & 63;
  const int q = lane >> 4, l15 = lane & 15;
  const int len = read_len(lenp, b);

  // Whh B-fragments resident in VGPRs: [pp][kc], h tiles 2w+pp, t tiles 16+2w+pp
  f16x8 Bh[2][8], Bt[2][8];
#pragma unroll
  for (int pp = 0; pp < 2; pp++)
#pragma unroll
    for (int kc = 0; kc < 8; kc++) {
      Bh[pp][kc] = *(const f16x8*)(bblob + ((size_t)((2 * w + pp) * 8 + kc) * 64 + lane) * 8);
      Bt[pp][kc] = *(const f16x8*)(bblob + ((size_t)((16 + 2 * w + pp) * 8 + kc) * 64 + lane) * 8);
    }

  __shared__ __align__(16) _Float16 hbuf[2][DIM];   // ping-pong h (1 KB total)
  if (tid < DIM) hbuf[0][tid] = (_Float16)0.f;
  __syncthreads();

  const int c0 = (2 * w) * 16 + l15;       // h-col of pp=0
  const int c1 = (2 * w + 1) * 16 + l15;   // h-col of pp=1
  const _Float16* xrow = xw + (size_t)b * NCOL;
  const size_t xstride = (size_t)BATCH * NCOL;

  float h0 = 0.f, h1 = 0.f;                // running h for cols c0, c1 (dup across q)
  const float K1 = 1.442695040888963f, K2 = 2.885390081777927f;

  // prefetch xw for t=0
  float xh0n = (float)xrow[c0],       xh1n = (float)xrow[c1];
  float xt0n = (float)xrow[c0 + 256], xt1n = (float)xrow[c1 + 256];

  for (int t = 0; t < T_STEPS; t++) {
    const float xh0 = xh0n, xh1 = xh1n, xt0 = xt0n, xt1 = xt1n;
    const _Float16* xnext = xrow + (size_t)((t + 1 < T_STEPS) ? t + 1 : t) * xstride;
    xh0n = (float)xnext[c0];       xh1n = (float)xnext[c1];
    xt0n = (float)xnext[c0 + 256]; xt1n = (float)xnext[c1 + 256];

    const int p = t & 1;
    f32x4 a0 = {0.f,0.f,0.f,0.f}, a1 = a0, a2 = a0, a3 = a0;
    const _Float16* hb = &hbuf[p][q * 8];
#pragma unroll
    for (int kc = 0; kc < 8; kc++) {
      f16x8 a = *(const f16x8*)(hb + kc * 32);   // broadcast within q-group
      a0 = __builtin_amdgcn_mfma_f32_16x16x32_f16(a, Bh[0][kc], a0, 0, 0, 0);
      a1 = __builtin_amdgcn_mfma_f32_16x16x32_f16(a, Bh[1][kc], a1, 0, 0, 0);
      a2 = __builtin_amdgcn_mfma_f32_16x16x32_f16(a, Bt[0][kc], a2, 0, 0, 0);
      a3 = __builtin_amdgcn_mfma_f32_16x16x32_f16(a, Bt[1][kc], a3, 0, 0, 0);
    }
    // epilogue (all lanes hold duplicates; reg 0 of any q is a valid row)
    const bool live = t < len;
    {
      float ph = a0[0] + xh0, pt = a2[0] + xt0;
      float phc = fminf(fmaxf(ph, -20.f), 20.f);
      float e1 = __builtin_amdgcn_exp2f(-K2 * phc);
      float e2 = __builtin_amdgcn_exp2f(-K1 * pt);
      float u1 = 1.f + e1;
      float rr = __builtin_amdgcn_rcpf(u1 * (1.f + e2));
      float ttg = (1.f - e1) * rr;
      float tg  = u1 * rr;
      float cg = 0.5f + tg * (0.250905f + tg * (-0.00432f + tg * (-0.015525f)));
      float s = ttg + h0 * cg;
      h0 = live ? s : h0;
    }
    {
      float ph = a1[0] + xh1, pt = a3[0] + xt1;
      float phc = fminf(fmaxf(ph, -20.f), 20.f);
      float e1 = __builtin_amdgcn_exp2f(-K2 * phc);
      float e2 = __builtin_amdgcn_exp2f(-K1 * pt);
      float u1 = 1.f + e1;
      float rr = __builtin_amdgcn_rcpf(u1 * (1.f + e2));
      float ttg = (1.f - e1) * rr;
      float tg  = u1 * rr;
      float cg = 0.5f + tg * (0.250905f + tg * (-0.00432f + tg * (-0.015525f)));
      float s = ttg + h1 * cg;
      h1 = live ? s : h1;
    }
    _Float16 s0 = (_Float16)h0, s1 = (_Float16)h1;
    if (q == 0) {                           // 16 lanes publish + store
      hbuf[1 - p][c0] = s0;
      hbuf[1 - p][c1] = s1;
      size_t o = ((size_t)t * BATCH + b) * DIM;
      if (LAYER == 0) { out0[o + c0] = s0; out0[o + c1] = s1; }
      else            { out1[o + c0] = h0; out1[o + c1] = h1; }
    }
    __syncthreads();
  }

  if (q == 0) {
    hn[LAYER * (BATCH * DIM) + b * DIM + c0] = h0;
    hn[LAYER * (BATCH * DIM) + b * DIM + c1] = h1;
  }
}

extern "C" void kernel_launch(void* const* d_in, const int* in_sizes, int n_in,
                              void* d_out, int out_size, void* d_ws, size_t ws_size,
                              hipStream_t stream) {
  const float* input_ = (const float*)d_in[0];
  const void*  lenp   = d_in[1];
  const float* Wih0   = (const float*)d_in[2];
  const float* Whh0   = (const float*)d_in[3];
  const float* b0     = (const float*)d_in[4];
  const float* Wih1   = (const float*)d_in[5];
  const float* Whh1   = (const float*)d_in[6];
  const float* b1     = (const float*)d_in[7];
  float* out = (float*)d_out;
  char*  ws  = (char*)d_ws;

  _Float16* XW    = (_Float16*)(ws + XW_OFF);
  _Float16* Abuf  = (_Float16*)(ws + A_OFF);
  _Float16* blobs = (_Float16*)(ws + BLOB_OFF);   // [Wih0, Wih1, Whh0, Whh1]
  float* hn = out + M_ROWS * DIM;                 // d_out tail: h_n [2][32][256]

  cvt_f32_to_f16<<<16384, 256, 0, stream>>>(input_, Abuf, (int)(M_ROWS * DIM / 4));
  prep_blobs4<<<2048, 256, 0, stream>>>(Wih0, Wih1, Whh0, Whh1, blobs);
  gemm_xw<<<2048, 256, 0, stream>>>(Abuf, blobs + 0 * BLOB_ELT, b0, XW);
  recur<0><<<BATCH, 512, 0, stream>>>(XW, blobs + 2 * BLOB_ELT, lenp, Abuf, nullptr, hn);
  gemm_xw<<<2048, 256, 0, stream>>>(Abuf, blobs + 1 * BLOB_ELT, b1, XW);
  recur<1><<<BATCH, 512, 0, stream>>>(XW, blobs + 3 * BLOB_ELT, lenp, nullptr, out, hn);
}